// Round 1
// baseline (452.118 us; speedup 1.0000x reference)
//
#include <hip/hip_runtime.h>
#include <stdint.h>

#define NB 4096            // batch rows
#define NC 8192            // classes / text rows
#define ND 512             // feature dim
#define INV_TEMP (1.0f/0.07f)

typedef float  f32x4 __attribute__((ext_vector_type(4)));
typedef unsigned int u32x4 __attribute__((ext_vector_type(4)));

__device__ __forceinline__ unsigned short f2bf(float f) {
    unsigned int u = __float_as_uint(f);
    u += 0x7fffu + ((u >> 16) & 1u);          // RNE
    return (unsigned short)(u >> 16);
}
__device__ __forceinline__ float bflo(unsigned int u) {   // low 16 bits -> f32
    return __uint_as_float(u << 16);
}
__device__ __forceinline__ float bfhi(unsigned int u) {   // high 16 bits -> f32
    return __uint_as_float(u & 0xFFFF0000u);
}
// monotone float<->uint keys for atomicMax/Min on floats of any sign
__device__ __forceinline__ unsigned int fenc(float f) {
    const unsigned int u = __float_as_uint(f);
    return (u & 0x80000000u) ? ~u : (u | 0x80000000u);
}
__device__ __forceinline__ float fdec(unsigned int k) {
    return __uint_as_float((k & 0x80000000u) ? (k ^ 0x80000000u) : ~k);
}

// ---------------- init (fused path): zero accumulators, compute m ----------------
__global__ __launch_bounds__(1024) void k_init2(const int* __restrict__ idx,
                                                float* __restrict__ colsum,
                                                float* __restrict__ rv,
                                                float* __restrict__ rowsum0,
                                                float* __restrict__ Arow,
                                                float* __restrict__ Tsumv,
                                                unsigned int* __restrict__ rowmxK,
                                                unsigned int* __restrict__ rowmnK,
                                                float* __restrict__ scal) {
    __shared__ int red[1024];
    const int tid = threadIdx.x;
    int cnt = 0;
    for (int q = tid; q < NB; q += 1024) {
        colsum[q] = 0.f; rv[q] = 1.f;
        rowsum0[q] = 0.f; Arow[q] = 0.f; Tsumv[q] = 0.f;
        rowmxK[q] = 0u; rowmnK[q] = 0xFFFFFFFFu;
        cnt += (idx[q] == 1) ? 1 : 0;
    }
    red[tid] = cnt; __syncthreads();
    for (int s = 512; s > 0; s >>= 1) {
        if (tid < s) red[tid] += red[tid + s];
        __syncthreads();
    }
    if (tid == 0) {
        const int c1 = red[0];
        scal[0] = (float)c1 + 0.1f * (float)(NB - c1);   // m
        scal[1] = 0.f;                                   // asl accumulator
        scal[2] = 0.f;                                   // multiclass accumulator
        unsigned int* u = (unsigned int*)scal;
        u[4] = 0u; u[5] = 0u; u[6] = 0u; u[7] = 0u; u[8] = 0u;  // iter counters
    }
}

// ---------------- legacy init (fallback path) ----------------
__global__ __launch_bounds__(1024) void k_init(const int* __restrict__ idx,
                                               float* __restrict__ colsum,
                                               float* __restrict__ rv,
                                               float* __restrict__ scal) {
    __shared__ int red[1024];
    const int tid = threadIdx.x;
    int cnt = 0;
    for (int q = tid; q < NB; q += 1024) {
        colsum[q] = 0.f;
        rv[q] = 1.f;
        cnt += (idx[q] == 1) ? 1 : 0;
    }
    red[tid] = cnt; __syncthreads();
    for (int s = 512; s > 0; s >>= 1) {
        if (tid < s) red[tid] += red[tid + s];
        __syncthreads();
    }
    if (tid == 0) {
        const int c1 = red[0];
        scal[0] = (float)c1 + 0.1f * (float)(NB - c1);
        scal[1] = 0.f;
        scal[2] = 0.f;
    }
}

// ---------------- f32 -> bf16 convert, F and T in one launch ----------------
__global__ __launch_bounds__(256) void k_cvt2(const float4* __restrict__ F4,
                                              const float4* __restrict__ T4,
                                              unsigned short* __restrict__ Fb,
                                              unsigned short* __restrict__ Tb) {
    const int i  = blockIdx.x * 256 + threadIdx.x;
    const int nF = NB * ND / 4;
    const float4 v = (i < nF) ? F4[i] : T4[i - nF];
    union { unsigned short h[4]; uint2 u; } p;
    p.h[0] = f2bf(v.x); p.h[1] = f2bf(v.y); p.h[2] = f2bf(v.z); p.h[3] = f2bf(v.w);
    if (i < nF) ((uint2*)Fb)[i] = p.u;
    else        ((uint2*)Tb)[i - nF] = p.u;
}

// ---------------- legacy cvt (fallback path) ----------------
__global__ __launch_bounds__(256) void k_cvt(const float4* __restrict__ src,
                                             unsigned short* __restrict__ dst, int n4) {
    const int i = blockIdx.x * 256 + threadIdx.x;
    if (i >= n4) return;
    const float4 v = src[i];
    union { unsigned short h[4]; uint2 u; } p;
    p.h[0] = f2bf(v.x); p.h[1] = f2bf(v.y); p.h[2] = f2bf(v.z); p.h[3] = f2bf(v.w);
    ((uint2*)dst)[i] = p.u;
}

// ---------------- MEGA GEMM: sim + masked outputs + full stats fused ----------------
// 128x128 tile, BK=64, 4 waves (2x2), 16x16x32 MFMA, XOR-swizzled LDS,
// global_load_lds width 16. Epilogue computes per-element exp/ASL, writes
// coco/cifar, stages bf16 E tile in LDS (reusing lA/lB) for coalesced Ebf
// writes, accumulates per-row {sum e, sum t*e, sum t, max s, min s} and the
// iteration-0 column sums (cols < NB) via device atomics.
__global__ __launch_bounds__(256) void k_gemm_fused(const unsigned short* __restrict__ Fb,
                                                    const unsigned short* __restrict__ Tb,
                                                    const int* __restrict__ idx,
                                                    const float* __restrict__ tgt,
                                                    float* __restrict__ coco,
                                                    float* __restrict__ cifar,
                                                    unsigned short* __restrict__ Ebf,
                                                    float* __restrict__ colsum,
                                                    float* __restrict__ rowsum0,
                                                    float* __restrict__ simdiag,
                                                    float* __restrict__ Arow,
                                                    float* __restrict__ Tsumv,
                                                    unsigned int* __restrict__ rowmxK,
                                                    unsigned int* __restrict__ rowmnK,
                                                    float* __restrict__ scal) {
    __shared__ unsigned short lds[128 * 128];   // 32 KB: lA|lB in K-loop, E tile in epilogue
    __shared__ float lsred[4];
    unsigned short* lA = lds;
    unsigned short* lB = lds + 128 * 64;
    const int tid  = threadIdx.x;
    const int lane = tid & 63;
    const int wid  = tid >> 6;                // 0..3
    const int wm = wid >> 1, wn = wid & 1;    // 2x2 wave grid, 64x64 each
    const int brow = blockIdx.y * 128;
    const int bcol = blockIdx.x * 128;

    f32x4 acc[4][4] = {};

    for (int kt = 0; kt < ND / 64; ++kt) {
        if (kt) __syncthreads();
#pragma unroll
        for (int c = 0; c < 4; ++c) {
            const int ch  = c * 4 + wid;
            const int o   = ch * 1024 + lane * 16;   // linear LDS byte
            const int row = o >> 7;                  // 128 B per row
            const int kbu = (o & 127) ^ ((row & 7) << 4); // inverse-swizzled source
            const unsigned short* gA = Fb + ((size_t)(brow + row) << 9) + (kt << 5)*2 + (kbu >> 1);
            __builtin_amdgcn_global_load_lds(
                (const __attribute__((address_space(1))) unsigned int*)gA,
                (__attribute__((address_space(3))) unsigned int*)((char*)lA + ch * 1024),
                16, 0, 0);
            const unsigned short* gB = Tb + ((size_t)(bcol + row) << 9) + (kt << 5)*2 + (kbu >> 1);
            __builtin_amdgcn_global_load_lds(
                (const __attribute__((address_space(1))) unsigned int*)gB,
                (__attribute__((address_space(3))) unsigned int*)((char*)lB + ch * 1024),
                16, 0, 0);
        }
        __syncthreads();
#pragma unroll
        for (int ks = 0; ks < 2; ++ks) {
            u32x4 af[4], bfr[4];
#pragma unroll
            for (int mi = 0; mi < 4; ++mi) {
                const int row  = wm * 64 + mi * 16 + (lane & 15);
                const int kb   = ks * 64 + ((lane >> 4) << 4);
                const int addr = row * 128 + (kb ^ ((row & 7) << 4));
                af[mi] = *(const u32x4*)((const char*)lA + addr);
            }
#pragma unroll
            for (int ni = 0; ni < 4; ++ni) {
                const int row  = wn * 64 + ni * 16 + (lane & 15);
                const int kb   = ks * 64 + ((lane >> 4) << 4);
                const int addr = row * 128 + (kb ^ ((row & 7) << 4));
                bfr[ni] = *(const u32x4*)((const char*)lB + addr);
            }
#pragma unroll
            for (int mi = 0; mi < 4; ++mi)
#pragma unroll
                for (int ni = 0; ni < 4; ++ni)
                    asm("v_mfma_f32_16x16x32_bf16 %0, %1, %2, %0"
                        : "+v"(acc[mi][ni]) : "v"(af[mi]), "v"(bfr[ni]));
        }
    }
    asm volatile("s_nop 7\n\ts_nop 7\n\ts_nop 7" ::);   // MFMA->VALU hazard fence
    __syncthreads();                                     // LDS reuse fence (E tile)

    // ---- fused epilogue ----
    const int r0    = (lane >> 4) << 2;                  // 0,4,8,12
    const int cl0   = wn * 64 + (lane & 15);             // local col base
    float ls = 0.f;
    float colp[4] = {0.f, 0.f, 0.f, 0.f};
#pragma unroll
    for (int mi = 0; mi < 4; ++mi) {
        const int rl0 = wm * 64 + mi * 16 + r0;
#pragma unroll
        for (int rr = 0; rr < 4; ++rr) {
            const int rl  = rl0 + rr;
            const int row = brow + rl;
            const int isC = (idx[row] == 1);
            float rs = 0.f, a = 0.f, ts = 0.f;
            float mx = -3.4e38f, mn = 3.4e38f;
#pragma unroll
            for (int ni = 0; ni < 4; ++ni) {
                const int cl  = cl0 + ni * 16;
                const int col = bcol + cl;
                const float s = acc[mi][ni][rr] * INV_TEMP;
                const size_t o = (size_t)row * NC + col;
                coco[o]  = isC ? 0.0f : s;
                cifar[o] = isC ? s    : 0.0f;
                const float t = tgt[o];
                const float e = __expf(s);
                const unsigned short eb = f2bf(e);
                lds[rl * 128 + cl] = eb;
                if (row == col) simdiag[row] = s;
                rs += e; a += t * e; ts += t;
                mx = fmaxf(mx, s); mn = fminf(mn, s);
                colp[ni] += __uint_as_float((unsigned int)eb << 16);  // bf16-rounded, matches iter 2..5
                const float inv = __builtin_amdgcn_rcpf(1.0f + e);
                const float xsp = e * inv;
                const float xsn = fminf(1.05f - xsp, 1.0f);
                const float lp  = __logf(xsp);
                const float ln  = __logf(xsn);
                const float pt  = xsn + t * (xsp - xsn);
                const float g   = 4.0f - 3.0f * t;
                const float pw  = __builtin_amdgcn_exp2f(g * __builtin_amdgcn_logf(1.0f - pt));
                ls += (ln + t * (lp - ln)) * pw;
            }
#pragma unroll
            for (int off = 1; off < 16; off <<= 1) {   // reduce across the 16 lanes of this row
                rs += __shfl_xor(rs, off);
                a  += __shfl_xor(a,  off);
                ts += __shfl_xor(ts, off);
                mx = fmaxf(mx, __shfl_xor(mx, off));
                mn = fminf(mn, __shfl_xor(mn, off));
            }
            if ((lane & 15) == 0) {
                atomicAdd(&rowsum0[row], rs);
                atomicAdd(&Arow[row],    a);
                atomicAdd(&Tsumv[row],   ts);
                atomicMax(&rowmxK[row], fenc(mx));
                atomicMin(&rowmnK[row], fenc(mn));
            }
        }
    }
    // iteration-0 column sums (r == 1), only the first NB columns are ever used
    if (bcol < NB) {
#pragma unroll
        for (int ni = 0; ni < 4; ++ni) {
            colp[ni] += __shfl_xor(colp[ni], 16);
            colp[ni] += __shfl_xor(colp[ni], 32);
        }
        if (lane < 16) {
#pragma unroll
            for (int ni = 0; ni < 4; ++ni)
                atomicAdd(&colsum[bcol + wn * 64 + ni * 16 + lane], colp[ni]);
        }
    }
    // block ASL reduce
#pragma unroll
    for (int off = 1; off < 64; off <<= 1) ls += __shfl_xor(ls, off);
    if (lane == 0) lsred[wid] = ls;
    __syncthreads();                                   // lsred + E tile visible
    if (tid == 0) atomicAdd(&scal[1], lsred[0] + lsred[1] + lsred[2] + lsred[3]);
    // coalesced Ebf tile write from LDS: 16 lanes = one 256 B row chunk
#pragma unroll
    for (int p = 0; p < 8; ++p) {
        const int cidx = tid + p * 256;
        const int r = cidx >> 4, ch = cidx & 15;
        *(uint4*)((char*)(Ebf + (size_t)(brow + r) * NC + bcol) + ch * 16) =
            *(const uint4*)((const char*)lds + r * 256 + ch * 16);
    }
}

// ---------------- legacy GEMM (fallback path) ----------------
__global__ __launch_bounds__(256) void k_gemm(const unsigned short* __restrict__ Fb,
                                              const unsigned short* __restrict__ Tb,
                                              const int* __restrict__ idx,
                                              float* __restrict__ sim,
                                              float* __restrict__ coco,
                                              float* __restrict__ cifar,
                                              int fused) {
    __shared__ unsigned short lA[128 * 64];
    __shared__ unsigned short lB[128 * 64];
    const int tid  = threadIdx.x;
    const int lane = tid & 63;
    const int wid  = tid >> 6;
    const int wm = wid >> 1, wn = wid & 1;
    const int brow = blockIdx.y * 128;
    const int bcol = blockIdx.x * 128;

    f32x4 acc[4][4] = {};

    for (int kt = 0; kt < ND / 64; ++kt) {
        if (kt) __syncthreads();
#pragma unroll
        for (int c = 0; c < 4; ++c) {
            const int ch  = c * 4 + wid;
            const int o   = ch * 1024 + lane * 16;
            const int row = o >> 7;
            const int kbu = (o & 127) ^ ((row & 7) << 4);
            const unsigned short* gA = Fb + ((size_t)(brow + row) << 9) + (kt << 5)*2 + (kbu >> 1);
            __builtin_amdgcn_global_load_lds(
                (const __attribute__((address_space(1))) unsigned int*)gA,
                (__attribute__((address_space(3))) unsigned int*)((char*)lA + ch * 1024),
                16, 0, 0);
            const unsigned short* gB = Tb + ((size_t)(bcol + row) << 9) + (kt << 5)*2 + (kbu >> 1);
            __builtin_amdgcn_global_load_lds(
                (const __attribute__((address_space(1))) unsigned int*)gB,
                (__attribute__((address_space(3))) unsigned int*)((char*)lB + ch * 1024),
                16, 0, 0);
        }
        __syncthreads();
#pragma unroll
        for (int ks = 0; ks < 2; ++ks) {
            u32x4 af[4], bfr[4];
#pragma unroll
            for (int mi = 0; mi < 4; ++mi) {
                const int row  = wm * 64 + mi * 16 + (lane & 15);
                const int kb   = ks * 64 + ((lane >> 4) << 4);
                const int addr = row * 128 + (kb ^ ((row & 7) << 4));
                af[mi] = *(const u32x4*)((const char*)lA + addr);
            }
#pragma unroll
            for (int ni = 0; ni < 4; ++ni) {
                const int row  = wn * 64 + ni * 16 + (lane & 15);
                const int kb   = ks * 64 + ((lane >> 4) << 4);
                const int addr = row * 128 + (kb ^ ((row & 7) << 4));
                bfr[ni] = *(const u32x4*)((const char*)lB + addr);
            }
#pragma unroll
            for (int mi = 0; mi < 4; ++mi)
#pragma unroll
                for (int ni = 0; ni < 4; ++ni)
                    asm("v_mfma_f32_16x16x32_bf16 %0, %1, %2, %0"
                        : "+v"(acc[mi][ni]) : "v"(af[mi]), "v"(bfr[ni]));
        }
    }
    asm volatile("s_nop 7\n\ts_nop 7\n\ts_nop 7" ::);
    if (fused) {
#pragma unroll
        for (int mi = 0; mi < 4; ++mi) {
            const int rb = brow + wm * 64 + mi * 16 + ((lane >> 4) << 2);
            int fl[4];
#pragma unroll
            for (int rr = 0; rr < 4; ++rr) fl[rr] = (idx[rb + rr] == 1);
#pragma unroll
            for (int ni = 0; ni < 4; ++ni) {
                const int col = bcol + wn * 64 + ni * 16 + (lane & 15);
#pragma unroll
                for (int rr = 0; rr < 4; ++rr) {
                    const float s = acc[mi][ni][rr] * INV_TEMP;
                    const size_t o = (size_t)(rb + rr) * NC + col;
                    coco[o]  = fl[rr] ? 0.0f : s;
                    cifar[o] = fl[rr] ? s : 0.0f;
                }
            }
        }
    } else {
#pragma unroll
        for (int mi = 0; mi < 4; ++mi) {
            const int rb = brow + wm * 64 + mi * 16 + ((lane >> 4) << 2);
#pragma unroll
            for (int ni = 0; ni < 4; ++ni) {
                const int col = bcol + wn * 64 + ni * 16 + (lane & 15);
#pragma unroll
                for (int rr = 0; rr < 4; ++rr)
                    sim[(size_t)(rb + rr) * NC + col] = acc[mi][ni][rr] * INV_TEMP;
            }
        }
    }
}

// ---------------- legacy per-row stats (fallback path) ----------------
__global__ __launch_bounds__(256) void k_stats(const float* __restrict__ pc,
                                               const float* __restrict__ pf,
                                               const int* __restrict__ idx,
                                               const float* __restrict__ tgt,
                                               unsigned short* __restrict__ Ebf,
                                               float* __restrict__ rowsum0,
                                               float* __restrict__ simdiag,
                                               float* __restrict__ Arow,
                                               float* __restrict__ Tsumv,
                                               float* __restrict__ rowmx,
                                               float* __restrict__ rowmn,
                                               float* __restrict__ scal) {
    const int i = blockIdx.x, tid = threadIdx.x;
    const float* srow = ((idx[i] == 1) ? pf : pc) + (size_t)i * NC;
    const float* trow = tgt + (size_t)i * NC;
    unsigned short* erow = Ebf ? (Ebf + (size_t)i * NC) : nullptr;
    float rs = 0.f, a = 0.f, ts = 0.f, ls = 0.f;
    float mx = -3.4e38f, mn = 3.4e38f;
    for (int c = tid * 4; c < NC; c += 1024) {
        const float s0 = srow[c], s1 = srow[c+1], s2 = srow[c+2], s3 = srow[c+3];
        const float4 t4 = *(const float4*)(trow + c);
        const float t0 = t4.x, t1 = t4.y, t2 = t4.z, t3 = t4.w;
        if ((unsigned)(i - c) < 4u)
            simdiag[i] = (i == c) ? s0 : ((i == c+1) ? s1 : ((i == c+2) ? s2 : s3));
        float e0, e1, e2, e3;
#define ASL(sv, tv, ev) { \
        ev = __expf(sv); \
        rs += ev; a += (tv) * ev; ts += (tv); \
        mx = fmaxf(mx, (sv)); mn = fminf(mn, (sv)); \
        const float inv = __builtin_amdgcn_rcpf(1.0f + ev); \
        const float xsp = ev * inv; \
        const float xsn = fminf(1.05f - xsp, 1.0f); \
        const float lp  = __logf(xsp); \
        const float ln  = __logf(xsn); \
        const float pt  = xsn + (tv) * (xsp - xsn); \
        const float g   = 4.0f - 3.0f * (tv); \
        const float pw  = __builtin_amdgcn_exp2f(g * __builtin_amdgcn_logf(1.0f - pt)); \
        ls += (ln + (tv) * (lp - ln)) * pw; }
        ASL(s0, t0, e0) ASL(s1, t1, e1) ASL(s2, t2, e2) ASL(s3, t3, e3)
#undef ASL
        if (erow) {
            uint2 w;
            w.x = (unsigned)f2bf(e0) | ((unsigned)f2bf(e1) << 16);
            w.y = (unsigned)f2bf(e2) | ((unsigned)f2bf(e3) << 16);
            *(uint2*)(erow + c) = w;
        }
    }
#pragma unroll
    for (int off = 1; off < 64; off <<= 1) {
        rs += __shfl_xor(rs, off);
        a  += __shfl_xor(a , off);
        ts += __shfl_xor(ts, off);
        ls += __shfl_xor(ls, off);
        mx = fmaxf(mx, __shfl_xor(mx, off));
        mn = fminf(mn, __shfl_xor(mn, off));
    }
    __shared__ float red[4][6];
    if ((tid & 63) == 0) {
        const int w = tid >> 6;
        red[w][0] = rs; red[w][1] = a; red[w][2] = ts;
        red[w][3] = ls; red[w][4] = mx; red[w][5] = mn;
    }
    __syncthreads();
    if (tid == 0) {
        rowsum0[i] = red[0][0] + red[1][0] + red[2][0] + red[3][0];
        Arow[i]    = red[0][1] + red[1][1] + red[2][1] + red[3][1];
        Tsumv[i]   = red[0][2] + red[1][2] + red[2][2] + red[3][2];
        atomicAdd(&scal[1], red[0][3] + red[1][3] + red[2][3] + red[3][3]);
        rowmx[i] = fmaxf(fmaxf(red[0][4], red[1][4]), fmaxf(red[2][4], red[3][4]));
        rowmn[i] = fminf(fminf(red[0][5], red[1][5]), fminf(red[2][5], red[3][5]));
    }
}

// ---------------- fallback colsum (no E buffer) ----------------
__global__ __launch_bounds__(256) void k_colsum(const float* __restrict__ pc,
                                                const float* __restrict__ pf,
                                                const int* __restrict__ idx,
                                                const float* __restrict__ rv,
                                                float* __restrict__ colsum) {
    const int j  = (blockIdx.x * 256 + threadIdx.x) * 4;
    const int i0 = blockIdx.y * 32;
    float a0 = 0.f, a1 = 0.f, a2 = 0.f, a3 = 0.f;
    for (int i = i0; i < i0 + 32; ++i) {
        const float* row = ((idx[i] == 1) ? pf : pc) + (size_t)i * NC;
        const float r = rv[i];
        a0 += __expf(row[j    ]) * r;
        a1 += __expf(row[j + 1]) * r;
        a2 += __expf(row[j + 2]) * r;
        a3 += __expf(row[j + 3]) * r;
    }
    atomicAdd(&colsum[j    ], a0);
    atomicAdd(&colsum[j + 1], a1);
    atomicAdd(&colsum[j + 2], a2);
    atomicAdd(&colsum[j + 3], a3);
}

// ---------------- per-iteration scalar update of r (1 block) ----------------
__global__ __launch_bounds__(1024) void k_update(const float* __restrict__ simdiag,
                                                 float* __restrict__ colsum,
                                                 const float* __restrict__ rowsum0,
                                                 float* __restrict__ rv,
                                                 const float* __restrict__ scal) {
    __shared__ float red[1024];
    const int tid = threadIdx.x;
    float part = 0.f;
    float rl[4];
#pragma unroll
    for (int q = 0; q < 4; ++q) {
        const int i = tid + q * 1024;
        const float d  = fminf(simdiag[i] / colsum[i], 1.0f);
        const float rn = rv[i] * d;
        rl[q] = rn;
        part += rn * rowsum0[i];
        colsum[i] = 0.f;
    }
    red[tid] = part; __syncthreads();
    for (int s = 512; s > 0; s >>= 1) {
        if (tid < s) red[tid] += red[tid + s];
        __syncthreads();
    }
    const float sc = scal[0] / red[0];
#pragma unroll
    for (int q = 0; q < 4; ++q) rv[tid + q * 1024] = rl[q] * sc;
}

// ---------------- fused colsum + update: last block finishes the iteration ----------------
__global__ __launch_bounds__(256) void k_iter(const unsigned short* __restrict__ Ebf,
                                              float* __restrict__ rv,
                                              float* __restrict__ colsum,
                                              const float* __restrict__ simdiag,
                                              const float* __restrict__ rowsum0,
                                              const float* __restrict__ scal,
                                              unsigned int* __restrict__ cnt) {
    const int tid = threadIdx.x;
    const int j   = (blockIdx.x * 256 + tid) * 4;   // gridx = 4 -> j < 4096
    const int i0  = blockIdx.y * 64;                // gridy = 64
    float a0 = 0.f, a1 = 0.f, a2 = 0.f, a3 = 0.f;
    for (int i = i0; i < i0 + 64; ++i) {
        const uint2 u = *(const uint2*)(Ebf + (size_t)i * NC + j);
        const float r = rv[i];
        a0 += bflo(u.x) * r;
        a1 += bfhi(u.x) * r;
        a2 += bflo(u.y) * r;
        a3 += bfhi(u.y) * r;
    }
    atomicAdd(&colsum[j    ], a0);
    atomicAdd(&colsum[j + 1], a1);
    atomicAdd(&colsum[j + 2], a2);
    atomicAdd(&colsum[j + 3], a3);
    __threadfence();                                // release our colsum atomics
    __shared__ int isLast;
    __syncthreads();
    if (tid == 0) isLast = (atomicAdd(cnt, 1u) == 255u);
    __syncthreads();
    if (!isLast) return;
    __threadfence();                                // acquire
    float part = 0.f;
    float rl[16];
#pragma unroll
    for (int q = 0; q < 16; ++q) {
        const int i = q * 256 + tid;
        const float cs = atomicAdd(&colsum[i], 0.0f);   // L2-coherent read
        const float d  = fminf(simdiag[i] / cs, 1.0f);
        const float rn = rv[i] * d;
        rl[q] = rn;
        part += rn * rowsum0[i];
        colsum[i] = 0.f;                            // reset for next iteration
    }
#pragma unroll
    for (int off = 1; off < 64; off <<= 1) part += __shfl_xor(part, off);
    __shared__ float red[4];
    if ((tid & 63) == 0) red[tid >> 6] = part;
    __syncthreads();
    const float S  = red[0] + red[1] + red[2] + red[3];
    const float sc = scal[0] / S;
#pragma unroll
    for (int q = 0; q < 16; ++q) rv[q * 256 + tid] = rl[q] * sc;
}

// ---------------- logsumexp(P row) + multiclass accumulation, bf16 E, key-encoded max/min ----------------
__global__ __launch_bounds__(256) void k_rowfinal_e2(const unsigned short* __restrict__ Ebf,
                                                     const float* __restrict__ rv,
                                                     const float* __restrict__ Arow,
                                                     const float* __restrict__ Tsumv,
                                                     const unsigned int* __restrict__ rowmxK,
                                                     const unsigned int* __restrict__ rowmnK,
                                                     float* __restrict__ scal) {
    const int i = blockIdx.x, tid = threadIdx.x;
    const float ri = rv[i];
    const unsigned short* erow = Ebf + (size_t)i * NC;
    const float M = ri * __expf((ri >= 0.f) ? fdec(rowmxK[i]) : fdec(rowmnK[i]));
    float se = 0.f;
    for (int c = tid * 8; c < NC; c += 2048) {
        const uint4 u = *(const uint4*)(erow + c);
        se += __expf(ri * bflo(u.x) - M);
        se += __expf(ri * bfhi(u.x) - M);
        se += __expf(ri * bflo(u.y) - M);
        se += __expf(ri * bfhi(u.y) - M);
        se += __expf(ri * bflo(u.z) - M);
        se += __expf(ri * bfhi(u.z) - M);
        se += __expf(ri * bflo(u.w) - M);
        se += __expf(ri * bfhi(u.w) - M);
    }
#pragma unroll
    for (int off = 1; off < 64; off <<= 1) se += __shfl_xor(se, off);
    __shared__ float red[4];
    if ((tid & 63) == 0) red[tid >> 6] = se;
    __syncthreads();
    if (tid == 0) {
        const float L = M + __logf(red[0] + red[1] + red[2] + red[3]);
        atomicAdd(&scal[2], Tsumv[i] * L - ri * Arow[i]);
    }
}

// ---------------- fallback rowfinal (float max/min, no E buffer) ----------------
__global__ __launch_bounds__(256) void k_rowfinal(const float* __restrict__ pc,
                                                  const float* __restrict__ pf,
                                                  const int* __restrict__ idx,
                                                  const float* __restrict__ rv,
                                                  const float* __restrict__ Arow,
                                                  const float* __restrict__ Tsumv,
                                                  const float* __restrict__ rowmx,
                                                  const float* __restrict__ rowmn,
                                                  float* __restrict__ scal) {
    const int i = blockIdx.x, tid = threadIdx.x;
    const float ri = rv[i];
    const float* srow = ((idx[i] == 1) ? pf : pc) + (size_t)i * NC;
    const float M = ri * __expf((ri >= 0.f) ? rowmx[i] : rowmn[i]);
    float se = 0.f;
    for (int c = tid * 4; c < NC; c += 1024) {
        se += __expf(ri * __expf(srow[c    ]) - M);
        se += __expf(ri * __expf(srow[c + 1]) - M);
        se += __expf(ri * __expf(srow[c + 2]) - M);
        se += __expf(ri * __expf(srow[c + 3]) - M);
    }
#pragma unroll
    for (int off = 1; off < 64; off <<= 1) se += __shfl_xor(se, off);
    __shared__ float red[4];
    if ((tid & 63) == 0) red[tid >> 6] = se;
    __syncthreads();
    if (tid == 0) {
        const float L = M + __logf(red[0] + red[1] + red[2] + red[3]);
        atomicAdd(&scal[2], Tsumv[i] * L - ri * Arow[i]);
    }
}

// ---------------- final scalars ----------------
__global__ void k_scalars(const float* __restrict__ scal, float* __restrict__ out) {
    if (threadIdx.x == 0) {
        const float mc = scal[2] / (float)NB;
        const float ml = -scal[1];
        out[0] = mc + ml;
        out[1] = mc;
        out[2] = ml;
    }
}

// ---------------- masked sim outputs (fallback path; sim aliases cifar) ----------------
__global__ __launch_bounds__(256) void k_mask(const float* sim, const int* idx,
                                              float* coco, float* cifar) {
    const int i = blockIdx.y;
    const int c = blockIdx.x * 256 + threadIdx.x;
    const size_t o = (size_t)i * NC + c;
    const float s = sim[o];
    const bool isCifar = (idx[i] == 1);
    coco[o]  = isCifar ? 0.0f : s;
    cifar[o] = isCifar ? s : 0.0f;
}

extern "C" void kernel_launch(void* const* d_in, const int* in_sizes, int n_in,
                              void* d_out, int out_size, void* d_ws, size_t ws_size,
                              hipStream_t stream) {
    const float* F   = (const float*)d_in[0];   // [4096,512]
    const float* T   = (const float*)d_in[1];   // [8192,512]
    const float* tgt = (const float*)d_in[2];   // [4096,8192]
    const int*   idx = (const int*)d_in[3];     // [4096]

    float* out   = (float*)d_out;
    float* coco  = out + 3;
    float* cifar = coco + (size_t)NB * NC;

    const size_t FbBytes    = (size_t)NB * ND * 2;      // 4 MB
    const size_t TbBytes    = (size_t)NC * ND * 2;      // 8 MB
    const size_t EBytes     = (size_t)NB * NC * 2;      // 67 MB
    const size_t smallBytes = 10 * (size_t)NB * 4 + 1024;

    const bool fused = (d_ws != nullptr) &&
                       (ws_size >= FbBytes + TbBytes + smallBytes + 512);
    const bool hasE  = (d_ws != nullptr) &&
                       (ws_size >= FbBytes + TbBytes + EBytes + smallBytes + 512);
    unsigned short *Fb, *Tb, *Ebf = nullptr;
    float *sm, *sim;
    if (fused) {
        Fb  = (unsigned short*)d_ws;
        Tb  = (unsigned short*)((char*)d_ws + FbBytes);
        char* p = (char*)d_ws + FbBytes + TbBytes;
        if (hasE) { Ebf = (unsigned short*)p; p += EBytes; }
        sm  = (float*)p;
        sim = nullptr;
    } else {
        sim = cifar;
        char* base = (char*)(((uintptr_t)(void*)coco + 255) & ~(uintptr_t)255);
        Fb  = (unsigned short*)base;
        Tb  = (unsigned short*)(base + FbBytes);
        sm  = (float*)(base + FbBytes + TbBytes);
    }
    float* colsum  = sm;
    float* rv      = sm + NB;
    float* rowsum0 = sm + 2 * NB;
    float* simdiag = sm + 3 * NB;
    float* Arow    = sm + 4 * NB;
    float* Tsumv   = sm + 5 * NB;
    float* rowmx   = sm + 6 * NB;
    float* rowmn   = sm + 7 * NB;
    float* scal    = sm + 8 * NB;

    if (hasE) {
        // ---- fused mega path ----
        k_init2<<<1, 1024, 0, stream>>>(idx, colsum, rv, rowsum0, Arow, Tsumv,
                                        (unsigned int*)rowmx, (unsigned int*)rowmn, scal);
        k_cvt2<<<((NB + NC) * ND / 4) / 256, 256, 0, stream>>>((const float4*)F,
                                                               (const float4*)T, Fb, Tb);
        k_gemm_fused<<<dim3(NC / 128, NB / 128), 256, 0, stream>>>(
            Fb, Tb, idx, tgt, coco, cifar, Ebf, colsum, rowsum0, simdiag, Arow, Tsumv,
            (unsigned int*)rowmx, (unsigned int*)rowmn, scal);
        k_update<<<1, 1024, 0, stream>>>(simdiag, colsum, rowsum0, rv, scal);  // iter 0
        for (int it = 1; it < 5; ++it)
            k_iter<<<dim3(NB / 1024, 64), 256, 0, stream>>>(Ebf, rv, colsum, simdiag,
                                                            rowsum0, scal,
                                                            (unsigned int*)scal + 4 + it);
        k_rowfinal_e2<<<NB, 256, 0, stream>>>(Ebf, rv, Arow, Tsumv,
                                              (const unsigned int*)rowmx,
                                              (const unsigned int*)rowmn, scal);
        k_scalars<<<1, 64, 0, stream>>>(scal, out);
        return;
    }

    // ---- fallback paths (no E buffer) ----
    const float* pc = fused ? coco  : sim;
    const float* pf = fused ? cifar : sim;

    k_init<<<1, 1024, 0, stream>>>(idx, colsum, rv, scal);
    k_cvt<<<(NB * ND / 4) / 256, 256, 0, stream>>>((const float4*)F, Fb, NB * ND / 4);
    k_cvt<<<(NC * ND / 4) / 256, 256, 0, stream>>>((const float4*)T, Tb, NC * ND / 4);
    k_gemm<<<dim3(NC / 128, NB / 128), 256, 0, stream>>>(Fb, Tb, idx, sim, coco, cifar,
                                                         fused ? 1 : 0);
    k_stats<<<NB, 256, 0, stream>>>(pc, pf, idx, tgt, nullptr, rowsum0, simdiag, Arow, Tsumv,
                                    rowmx, rowmn, scal);
    for (int it = 0; it < 5; ++it) {
        k_colsum<<<dim3(NB / 1024, 128), 256, 0, stream>>>(pc, pf, idx, rv, colsum);
        k_update<<<1, 1024, 0, stream>>>(simdiag, colsum, rowsum0, rv, scal);
    }
    k_rowfinal<<<NB, 256, 0, stream>>>(pc, pf, idx, rv, Arow, Tsumv, rowmx, rowmn, scal);
    k_scalars<<<1, 64, 0, stream>>>(scal, out);
    if (!fused) k_mask<<<dim3(NC / 256, NB), 256, 0, stream>>>(sim, idx, coco, cifar);
}

// Round 2
// 448.443 us; speedup vs baseline: 1.0082x; 1.0082x over previous
//
#include <hip/hip_runtime.h>
#include <stdint.h>

#define NB 4096            // batch rows
#define NC 8192            // classes / text rows
#define ND 512             // feature dim
#define INV_TEMP (1.0f/0.07f)

typedef float  f32x4 __attribute__((ext_vector_type(4)));
typedef unsigned int u32x4 __attribute__((ext_vector_type(4)));

__device__ __forceinline__ unsigned short f2bf(float f) {
    unsigned int u = __float_as_uint(f);
    u += 0x7fffu + ((u >> 16) & 1u);          // RNE
    return (unsigned short)(u >> 16);
}
__device__ __forceinline__ float bflo(unsigned int u) {   // low 16 bits -> f32
    return __uint_as_float(u << 16);
}
__device__ __forceinline__ float bfhi(unsigned int u) {   // high 16 bits -> f32
    return __uint_as_float(u & 0xFFFF0000u);
}

// ---------------- init: zero accumulators, iter counters, compute m ----------------
__global__ __launch_bounds__(1024) void k_init2(const int* __restrict__ idx,
                                                float* __restrict__ colsum,
                                                float* __restrict__ rv,
                                                float* __restrict__ scal) {
    __shared__ int red[1024];
    const int tid = threadIdx.x;
    int cnt = 0;
    for (int q = tid; q < NB; q += 1024) {
        colsum[q] = 0.f;
        rv[q] = 1.f;
        cnt += (idx[q] == 1) ? 1 : 0;
    }
    red[tid] = cnt; __syncthreads();
    for (int s = 512; s > 0; s >>= 1) {
        if (tid < s) red[tid] += red[tid + s];
        __syncthreads();
    }
    if (tid == 0) {
        const int c1 = red[0];
        scal[0] = (float)c1 + 0.1f * (float)(NB - c1);   // m
        scal[1] = 0.f;                                   // asl accumulator
        scal[2] = 0.f;                                   // multiclass accumulator
        unsigned int* u = (unsigned int*)scal;
        u[4] = 0u; u[5] = 0u; u[6] = 0u; u[7] = 0u; u[8] = 0u;  // k_iter counters
    }
}

// ---------------- f32 -> bf16 convert, F and T in one launch ----------------
__global__ __launch_bounds__(256) void k_cvt2(const float4* __restrict__ F4,
                                              const float4* __restrict__ T4,
                                              unsigned short* __restrict__ Fb,
                                              unsigned short* __restrict__ Tb) {
    const int i  = blockIdx.x * 256 + threadIdx.x;
    const int nF = NB * ND / 4;
    const float4 v = (i < nF) ? F4[i] : T4[i - nF];
    union { unsigned short h[4]; uint2 u; } p;
    p.h[0] = f2bf(v.x); p.h[1] = f2bf(v.y); p.h[2] = f2bf(v.z); p.h[3] = f2bf(v.w);
    if (i < nF) ((uint2*)Fb)[i] = p.u;
    else        ((uint2*)Tb)[i - nF] = p.u;
}

// ---------------- legacy cvt (fallback path) ----------------
__global__ __launch_bounds__(256) void k_cvt(const float4* __restrict__ src,
                                             unsigned short* __restrict__ dst, int n4) {
    const int i = blockIdx.x * 256 + threadIdx.x;
    if (i >= n4) return;
    const float4 v = src[i];
    union { unsigned short h[4]; uint2 u; } p;
    p.h[0] = f2bf(v.x); p.h[1] = f2bf(v.y); p.h[2] = f2bf(v.z); p.h[3] = f2bf(v.w);
    ((uint2*)dst)[i] = p.u;
}

// ---------------- GEMM: sim = (F @ T^T) * (1/0.07), bf16 MFMA ----------------
// 128x128 tile, BK=64, 4 waves (2x2), 16x16x32 MFMA, XOR-swizzled LDS,
// global_load_lds width 16 with pre-swizzled global source.
// fused=1: write masked coco/cifar directly (no sim buffer, no mask pass).
__global__ __launch_bounds__(256) void k_gemm(const unsigned short* __restrict__ Fb,
                                              const unsigned short* __restrict__ Tb,
                                              const int* __restrict__ idx,
                                              float* __restrict__ sim,
                                              float* __restrict__ coco,
                                              float* __restrict__ cifar,
                                              int fused) {
    __shared__ unsigned short lA[128 * 64];   // 16 KB, [row][k] bf16, swizzled
    __shared__ unsigned short lB[128 * 64];   // 16 KB
    const int tid  = threadIdx.x;
    const int lane = tid & 63;
    const int wid  = tid >> 6;                // 0..3
    const int wm = wid >> 1, wn = wid & 1;    // 2x2 wave grid, 64x64 each
    const int brow = blockIdx.y * 128;
    const int bcol = blockIdx.x * 128;

    f32x4 acc[4][4] = {};

    for (int kt = 0; kt < ND / 64; ++kt) {
        if (kt) __syncthreads();
#pragma unroll
        for (int c = 0; c < 4; ++c) {
            const int ch  = c * 4 + wid;
            const int o   = ch * 1024 + lane * 16;   // linear LDS byte
            const int row = o >> 7;                  // 128 B per row
            const int kbu = (o & 127) ^ ((row & 7) << 4); // inverse-swizzled source
            const unsigned short* gA = Fb + ((size_t)(brow + row) << 9) + (kt << 5)*2 + (kbu >> 1);
            __builtin_amdgcn_global_load_lds(
                (const __attribute__((address_space(1))) unsigned int*)gA,
                (__attribute__((address_space(3))) unsigned int*)((char*)lA + ch * 1024),
                16, 0, 0);
            const unsigned short* gB = Tb + ((size_t)(bcol + row) << 9) + (kt << 5)*2 + (kbu >> 1);
            __builtin_amdgcn_global_load_lds(
                (const __attribute__((address_space(1))) unsigned int*)gB,
                (__attribute__((address_space(3))) unsigned int*)((char*)lB + ch * 1024),
                16, 0, 0);
        }
        __syncthreads();
#pragma unroll
        for (int ks = 0; ks < 2; ++ks) {
            u32x4 af[4], bfr[4];
#pragma unroll
            for (int mi = 0; mi < 4; ++mi) {
                const int row  = wm * 64 + mi * 16 + (lane & 15);
                const int kb   = ks * 64 + ((lane >> 4) << 4);
                const int addr = row * 128 + (kb ^ ((row & 7) << 4));
                af[mi] = *(const u32x4*)((const char*)lA + addr);
            }
#pragma unroll
            for (int ni = 0; ni < 4; ++ni) {
                const int row  = wn * 64 + ni * 16 + (lane & 15);
                const int kb   = ks * 64 + ((lane >> 4) << 4);
                const int addr = row * 128 + (kb ^ ((row & 7) << 4));
                bfr[ni] = *(const u32x4*)((const char*)lB + addr);
            }
#pragma unroll
            for (int mi = 0; mi < 4; ++mi)
#pragma unroll
                for (int ni = 0; ni < 4; ++ni)
                    asm("v_mfma_f32_16x16x32_bf16 %0, %1, %2, %0"
                        : "+v"(acc[mi][ni]) : "v"(af[mi]), "v"(bfr[ni]));
        }
    }
    asm volatile("s_nop 7\n\ts_nop 7\n\ts_nop 7" ::);   // MFMA->VALU hazard fence
    if (fused) {
#pragma unroll
        for (int mi = 0; mi < 4; ++mi) {
            const int rb = brow + wm * 64 + mi * 16 + ((lane >> 4) << 2);
            int fl[4];
#pragma unroll
            for (int rr = 0; rr < 4; ++rr) fl[rr] = (idx[rb + rr] == 1);
#pragma unroll
            for (int ni = 0; ni < 4; ++ni) {
                const int col = bcol + wn * 64 + ni * 16 + (lane & 15);
#pragma unroll
                for (int rr = 0; rr < 4; ++rr) {
                    const float s = acc[mi][ni][rr] * INV_TEMP;
                    const size_t o = (size_t)(rb + rr) * NC + col;
                    coco[o]  = fl[rr] ? 0.0f : s;
                    cifar[o] = fl[rr] ? s : 0.0f;
                }
            }
        }
    } else {
#pragma unroll
        for (int mi = 0; mi < 4; ++mi) {
            const int rb = brow + wm * 64 + mi * 16 + ((lane >> 4) << 2);
#pragma unroll
            for (int ni = 0; ni < 4; ++ni) {
                const int col = bcol + wn * 64 + ni * 16 + (lane & 15);
#pragma unroll
                for (int rr = 0; rr < 4; ++rr)
                    sim[(size_t)(rb + rr) * NC + col] = acc[mi][ni][rr] * INV_TEMP;
            }
        }
    }
}

// ---------------- per-row stats + ASL loss (one block per row) ----------------
// Fast ASL: sigmoid from shared exp, pow via exp2/log2 builtins.
// Optionally writes Ebf[i][c] = bf16(exp(sim)) for reuse by colsum/rowfinal.
__global__ __launch_bounds__(256) void k_stats(const float* __restrict__ pc,
                                               const float* __restrict__ pf,
                                               const int* __restrict__ idx,
                                               const float* __restrict__ tgt,
                                               unsigned short* __restrict__ Ebf,
                                               float* __restrict__ rowsum0,
                                               float* __restrict__ simdiag,
                                               float* __restrict__ Arow,
                                               float* __restrict__ Tsumv,
                                               float* __restrict__ rowmx,
                                               float* __restrict__ rowmn,
                                               float* __restrict__ scal) {
    const int i = blockIdx.x, tid = threadIdx.x;
    const float* srow = ((idx[i] == 1) ? pf : pc) + (size_t)i * NC;
    const float* trow = tgt + (size_t)i * NC;
    unsigned short* erow = Ebf ? (Ebf + (size_t)i * NC) : nullptr;
    float rs = 0.f, a = 0.f, ts = 0.f, ls = 0.f;
    float mx = -3.4e38f, mn = 3.4e38f;
    for (int c = tid * 4; c < NC; c += 1024) {
        const float s0 = srow[c], s1 = srow[c+1], s2 = srow[c+2], s3 = srow[c+3];
        const float4 t4 = *(const float4*)(trow + c);
        const float t0 = t4.x, t1 = t4.y, t2 = t4.z, t3 = t4.w;
        if ((unsigned)(i - c) < 4u)
            simdiag[i] = (i == c) ? s0 : ((i == c+1) ? s1 : ((i == c+2) ? s2 : s3));
        float e0, e1, e2, e3;
#define ASL(sv, tv, ev) { \
        ev = __expf(sv); \
        rs += ev; a += (tv) * ev; ts += (tv); \
        mx = fmaxf(mx, (sv)); mn = fminf(mn, (sv)); \
        const float inv = __builtin_amdgcn_rcpf(1.0f + ev); \
        const float xsp = ev * inv; \
        const float xsn = fminf(1.05f - xsp, 1.0f); \
        const float lp  = __logf(xsp); \
        const float ln  = __logf(xsn); \
        const float pt  = xsn + (tv) * (xsp - xsn); \
        const float g   = 4.0f - 3.0f * (tv); \
        const float pw  = __builtin_amdgcn_exp2f(g * __builtin_amdgcn_logf(1.0f - pt)); \
        ls += (ln + (tv) * (lp - ln)) * pw; }
        ASL(s0, t0, e0) ASL(s1, t1, e1) ASL(s2, t2, e2) ASL(s3, t3, e3)
#undef ASL
        if (erow) {
            uint2 w;
            w.x = (unsigned)f2bf(e0) | ((unsigned)f2bf(e1) << 16);
            w.y = (unsigned)f2bf(e2) | ((unsigned)f2bf(e3) << 16);
            *(uint2*)(erow + c) = w;
        }
    }
#pragma unroll
    for (int off = 1; off < 64; off <<= 1) {
        rs += __shfl_xor(rs, off);
        a  += __shfl_xor(a , off);
        ts += __shfl_xor(ts, off);
        ls += __shfl_xor(ls, off);
        mx = fmaxf(mx, __shfl_xor(mx, off));
        mn = fminf(mn, __shfl_xor(mn, off));
    }
    __shared__ float red[4][6];
    if ((tid & 63) == 0) {
        const int w = tid >> 6;
        red[w][0] = rs; red[w][1] = a; red[w][2] = ts;
        red[w][3] = ls; red[w][4] = mx; red[w][5] = mn;
    }
    __syncthreads();
    if (tid == 0) {
        rowsum0[i] = red[0][0] + red[1][0] + red[2][0] + red[3][0];
        Arow[i]    = red[0][1] + red[1][1] + red[2][1] + red[3][1];
        Tsumv[i]   = red[0][2] + red[1][2] + red[2][2] + red[3][2];
        atomicAdd(&scal[1], red[0][3] + red[1][3] + red[2][3] + red[3][3]);
        rowmx[i] = fmaxf(fmaxf(red[0][4], red[1][4]), fmaxf(red[2][4], red[3][4]));
        rowmn[i] = fminf(fminf(red[0][5], red[1][5]), fminf(red[2][5], red[3][5]));
    }
}

// ---------------- fused colsum + update: last block finishes the iteration ----------------
// Ebf[:, :NB] only (colsum is consumed solely at diagonal indices < NB).
__global__ __launch_bounds__(256) void k_iter(const unsigned short* __restrict__ Ebf,
                                              float* __restrict__ rv,
                                              float* __restrict__ colsum,
                                              const float* __restrict__ simdiag,
                                              const float* __restrict__ rowsum0,
                                              const float* __restrict__ scal,
                                              unsigned int* __restrict__ cnt) {
    const int tid = threadIdx.x;
    const int j   = (blockIdx.x * 256 + tid) * 4;   // gridx = 4 -> j < 4096
    const int i0  = blockIdx.y * 64;                // gridy = 64
    float a0 = 0.f, a1 = 0.f, a2 = 0.f, a3 = 0.f;
    for (int i = i0; i < i0 + 64; ++i) {
        const uint2 u = *(const uint2*)(Ebf + (size_t)i * NC + j);
        const float r = rv[i];
        a0 += bflo(u.x) * r;
        a1 += bfhi(u.x) * r;
        a2 += bflo(u.y) * r;
        a3 += bfhi(u.y) * r;
    }
    atomicAdd(&colsum[j    ], a0);
    atomicAdd(&colsum[j + 1], a1);
    atomicAdd(&colsum[j + 2], a2);
    atomicAdd(&colsum[j + 3], a3);
    __threadfence();                                // release our colsum atomics
    __shared__ int isLast;
    __syncthreads();
    if (tid == 0) isLast = (atomicAdd(cnt, 1u) == 255u);
    __syncthreads();
    if (!isLast) return;
    __threadfence();                                // acquire
    float part = 0.f;
    float rl[16];
#pragma unroll
    for (int q = 0; q < 16; ++q) {
        const int i = q * 256 + tid;
        const float cs = atomicAdd(&colsum[i], 0.0f);   // L2-coherent read
        const float d  = fminf(simdiag[i] / cs, 1.0f);
        const float rn = rv[i] * d;
        rl[q] = rn;
        part += rn * rowsum0[i];
        colsum[i] = 0.f;                            // reset for next iteration
    }
#pragma unroll
    for (int off = 1; off < 64; off <<= 1) part += __shfl_xor(part, off);
    __shared__ float red[4];
    if ((tid & 63) == 0) red[tid >> 6] = part;
    __syncthreads();
    const float S  = red[0] + red[1] + red[2] + red[3];
    const float sc = scal[0] / S;
#pragma unroll
    for (int q = 0; q < 16; ++q) rv[q * 256 + tid] = rl[q] * sc;
}

// ---------------- fallback colsum (no E buffer) ----------------
__global__ __launch_bounds__(256) void k_colsum(const float* __restrict__ pc,
                                                const float* __restrict__ pf,
                                                const int* __restrict__ idx,
                                                const float* __restrict__ rv,
                                                float* __restrict__ colsum) {
    const int j  = (blockIdx.x * 256 + threadIdx.x) * 4;   // gridx = NB/1024 = 4
    const int i0 = blockIdx.y * 32;                        // gridy = 128
    float a0 = 0.f, a1 = 0.f, a2 = 0.f, a3 = 0.f;
    for (int i = i0; i < i0 + 32; ++i) {
        const float* row = ((idx[i] == 1) ? pf : pc) + (size_t)i * NC;
        const float r = rv[i];
        a0 += __expf(row[j    ]) * r;
        a1 += __expf(row[j + 1]) * r;
        a2 += __expf(row[j + 2]) * r;
        a3 += __expf(row[j + 3]) * r;
    }
    atomicAdd(&colsum[j    ], a0);
    atomicAdd(&colsum[j + 1], a1);
    atomicAdd(&colsum[j + 2], a2);
    atomicAdd(&colsum[j + 3], a3);
}

// ---------------- per-iteration scalar update of r (fallback path) ----------------
__global__ __launch_bounds__(1024) void k_update(const float* __restrict__ simdiag,
                                                 float* __restrict__ colsum,
                                                 const float* __restrict__ rowsum0,
                                                 float* __restrict__ rv,
                                                 const float* __restrict__ scal) {
    __shared__ float red[1024];
    const int tid = threadIdx.x;
    float part = 0.f;
    float rl[4];
#pragma unroll
    for (int q = 0; q < 4; ++q) {
        const int i = tid + q * 1024;
        const float d  = fminf(simdiag[i] / colsum[i], 1.0f);
        const float rn = rv[i] * d;
        rl[q] = rn;
        part += rn * rowsum0[i];
        colsum[i] = 0.f;                    // reset for next iteration
    }
    red[tid] = part; __syncthreads();
    for (int s = 512; s > 0; s >>= 1) {
        if (tid < s) red[tid] += red[tid + s];
        __syncthreads();
    }
    const float sc = scal[0] / red[0];      // m / P.sum()
#pragma unroll
    for (int q = 0; q < 4; ++q) rv[tid + q * 1024] = rl[q] * sc;
}

// ---------------- logsumexp(P row) + multiclass accumulation, from bf16 E ----------------
__global__ __launch_bounds__(256) void k_rowfinal_e(const unsigned short* __restrict__ Ebf,
                                                    const float* __restrict__ rv,
                                                    const float* __restrict__ Arow,
                                                    const float* __restrict__ Tsumv,
                                                    const float* __restrict__ rowmx,
                                                    const float* __restrict__ rowmn,
                                                    float* __restrict__ scal) {
    const int i = blockIdx.x, tid = threadIdx.x;
    const float ri = rv[i];
    const unsigned short* erow = Ebf + (size_t)i * NC;
    // max of P row: ri>=0 -> ri*exp(rowmax); ri<0 -> ri*exp(rowmin).
    // (bf16 E can exceed exp(rowmax) by ~0.4%; logsumexp stays valid for any finite M)
    const float M = ri * __expf((ri >= 0.f) ? rowmx[i] : rowmn[i]);
    float se = 0.f;
    for (int c = tid * 8; c < NC; c += 2048) {
        const uint4 u = *(const uint4*)(erow + c);
        se += __expf(ri * bflo(u.x) - M);
        se += __expf(ri * bfhi(u.x) - M);
        se += __expf(ri * bflo(u.y) - M);
        se += __expf(ri * bfhi(u.y) - M);
        se += __expf(ri * bflo(u.z) - M);
        se += __expf(ri * bfhi(u.z) - M);
        se += __expf(ri * bflo(u.w) - M);
        se += __expf(ri * bfhi(u.w) - M);
    }
#pragma unroll
    for (int off = 1; off < 64; off <<= 1) se += __shfl_xor(se, off);
    __shared__ float red[4];
    if ((tid & 63) == 0) red[tid >> 6] = se;
    __syncthreads();
    if (tid == 0) {
        const float L = M + __logf(red[0] + red[1] + red[2] + red[3]);
        atomicAdd(&scal[2], Tsumv[i] * L - ri * Arow[i]);
    }
}

// ---------------- fallback rowfinal (no E buffer) ----------------
__global__ __launch_bounds__(256) void k_rowfinal(const float* __restrict__ pc,
                                                  const float* __restrict__ pf,
                                                  const int* __restrict__ idx,
                                                  const float* __restrict__ rv,
                                                  const float* __restrict__ Arow,
                                                  const float* __restrict__ Tsumv,
                                                  const float* __restrict__ rowmx,
                                                  const float* __restrict__ rowmn,
                                                  float* __restrict__ scal) {
    const int i = blockIdx.x, tid = threadIdx.x;
    const float ri = rv[i];
    const float* srow = ((idx[i] == 1) ? pf : pc) + (size_t)i * NC;
    const float M = ri * __expf((ri >= 0.f) ? rowmx[i] : rowmn[i]);
    float se = 0.f;
    for (int c = tid * 4; c < NC; c += 1024) {
        se += __expf(ri * __expf(srow[c    ]) - M);
        se += __expf(ri * __expf(srow[c + 1]) - M);
        se += __expf(ri * __expf(srow[c + 2]) - M);
        se += __expf(ri * __expf(srow[c + 3]) - M);
    }
#pragma unroll
    for (int off = 1; off < 64; off <<= 1) se += __shfl_xor(se, off);
    __shared__ float red[4];
    if ((tid & 63) == 0) red[tid >> 6] = se;
    __syncthreads();
    if (tid == 0) {
        const float L = M + __logf(red[0] + red[1] + red[2] + red[3]);
        atomicAdd(&scal[2], Tsumv[i] * L - ri * Arow[i]);
    }
}

// ---------------- final scalars ----------------
__global__ void k_scalars(const float* __restrict__ scal, float* __restrict__ out) {
    if (threadIdx.x == 0) {
        const float mc = scal[2] / (float)NB;
        const float ml = -scal[1];
        out[0] = mc + ml;
        out[1] = mc;
        out[2] = ml;
    }
}

// ---------------- masked sim outputs (fallback path; sim aliases cifar) ----------------
__global__ __launch_bounds__(256) void k_mask(const float* sim, const int* idx,
                                              float* coco, float* cifar) {
    const int i = blockIdx.y;
    const int c = blockIdx.x * 256 + threadIdx.x;
    const size_t o = (size_t)i * NC + c;
    const float s = sim[o];                 // read before any aliased write
    const bool isCifar = (idx[i] == 1);
    coco[o]  = isCifar ? 0.0f : s;
    cifar[o] = isCifar ? s : 0.0f;
}

extern "C" void kernel_launch(void* const* d_in, const int* in_sizes, int n_in,
                              void* d_out, int out_size, void* d_ws, size_t ws_size,
                              hipStream_t stream) {
    const float* F   = (const float*)d_in[0];   // [4096,512]
    const float* T   = (const float*)d_in[1];   // [8192,512]
    const float* tgt = (const float*)d_in[2];   // [4096,8192]
    const int*   idx = (const int*)d_in[3];     // [4096]

    float* out   = (float*)d_out;
    float* coco  = out + 3;
    float* cifar = coco + (size_t)NB * NC;

    const size_t FbBytes    = (size_t)NB * ND * 2;      // 4 MB
    const size_t TbBytes    = (size_t)NC * ND * 2;      // 8 MB
    const size_t EBytes     = (size_t)NB * NC * 2;      // 67 MB
    const size_t smallBytes = 10 * (size_t)NB * 4 + 1024;

    const bool fused = (d_ws != nullptr) &&
                       (ws_size >= FbBytes + TbBytes + smallBytes + 512);
    const bool hasE  = (d_ws != nullptr) &&
                       (ws_size >= FbBytes + TbBytes + EBytes + smallBytes + 512);
    unsigned short *Fb, *Tb, *Ebf = nullptr;
    float *sm, *sim;
    if (fused) {
        Fb  = (unsigned short*)d_ws;
        Tb  = (unsigned short*)((char*)d_ws + FbBytes);
        char* p = (char*)d_ws + FbBytes + TbBytes;
        if (hasE) { Ebf = (unsigned short*)p; p += EBytes; }
        sm  = (float*)p;
        sim = nullptr;
    } else {
        // sim lives in the cifar output slot; bf16 copies + small vectors in the
        // coco slot head (dead until k_mask, which runs last).
        sim = cifar;
        char* base = (char*)(((uintptr_t)(void*)coco + 255) & ~(uintptr_t)255);
        Fb  = (unsigned short*)base;
        Tb  = (unsigned short*)(base + FbBytes);
        sm  = (float*)(base + FbBytes + TbBytes);
    }
    float* colsum  = sm;
    float* rv      = sm + NB;
    float* rowsum0 = sm + 2 * NB;
    float* simdiag = sm + 3 * NB;
    float* Arow    = sm + 4 * NB;
    float* Tsumv   = sm + 5 * NB;
    float* rowmx   = sm + 6 * NB;
    float* rowmn   = sm + 7 * NB;
    float* scal    = sm + 8 * NB;

    const float* pc = fused ? coco  : sim;
    const float* pf = fused ? cifar : sim;

    if (hasE) {
        k_init2<<<1, 1024, 0, stream>>>(idx, colsum, rv, scal);
        k_cvt2<<<((NB + NC) * ND / 4) / 256, 256, 0, stream>>>((const float4*)F,
                                                               (const float4*)T, Fb, Tb);
        k_gemm<<<dim3(NC / 128, NB / 128), 256, 0, stream>>>(Fb, Tb, idx, sim, coco, cifar, 1);
        k_stats<<<NB, 256, 0, stream>>>(pc, pf, idx, tgt, Ebf, rowsum0, simdiag, Arow, Tsumv,
                                        rowmx, rowmn, scal);
        for (int it = 0; it < 5; ++it)
            k_iter<<<dim3(NB / 1024, 64), 256, 0, stream>>>(Ebf, rv, colsum, simdiag,
                                                            rowsum0, scal,
                                                            (unsigned int*)scal + 4 + it);
        k_rowfinal_e<<<NB, 256, 0, stream>>>(Ebf, rv, Arow, Tsumv, rowmx, rowmn, scal);
        k_scalars<<<1, 64, 0, stream>>>(scal, out);
        return;
    }

    // ---- fallback paths (no E buffer) ----
    k_init2<<<1, 1024, 0, stream>>>(idx, colsum, rv, scal);
    k_cvt<<<(NB * ND / 4) / 256, 256, 0, stream>>>((const float4*)F, Fb, NB * ND / 4);
    k_cvt<<<(NC * ND / 4) / 256, 256, 0, stream>>>((const float4*)T, Tb, NC * ND / 4);
    k_gemm<<<dim3(NC / 128, NB / 128), 256, 0, stream>>>(Fb, Tb, idx, sim, coco, cifar,
                                                         fused ? 1 : 0);
    k_stats<<<NB, 256, 0, stream>>>(pc, pf, idx, tgt, nullptr, rowsum0, simdiag, Arow, Tsumv,
                                    rowmx, rowmn, scal);
    for (int it = 0; it < 5; ++it) {
        k_colsum<<<dim3(NB / 1024, 128), 256, 0, stream>>>(pc, pf, idx, rv, colsum);
        k_update<<<1, 1024, 0, stream>>>(simdiag, colsum, rowsum0, rv, scal);
    }
    k_rowfinal<<<NB, 256, 0, stream>>>(pc, pf, idx, rv, Arow, Tsumv, rowmx, rowmn, scal);
    k_scalars<<<1, 64, 0, stream>>>(scal, out);
    if (!fused) k_mask<<<dim3(NC / 256, NB), 256, 0, stream>>>(sim, idx, coco, cifar);
}

// Round 3
// 442.725 us; speedup vs baseline: 1.0212x; 1.0129x over previous
//
#include <hip/hip_runtime.h>
#include <stdint.h>

#define NB 4096            // batch rows
#define NC 8192            // classes / text rows
#define ND 512             // feature dim
#define INV_TEMP (1.0f/0.07f)

typedef float  f32x4 __attribute__((ext_vector_type(4)));
typedef unsigned int u32x4 __attribute__((ext_vector_type(4)));

__device__ __forceinline__ unsigned short f2bf(float f) {
    unsigned int u = __float_as_uint(f);
    u += 0x7fffu + ((u >> 16) & 1u);          // RNE
    return (unsigned short)(u >> 16);
}
__device__ __forceinline__ float bflo(unsigned int u) {   // low 16 bits -> f32
    return __uint_as_float(u << 16);
}
__device__ __forceinline__ float bfhi(unsigned int u) {   // high 16 bits -> f32
    return __uint_as_float(u & 0xFFFF0000u);
}

// ---------------- init: zero accumulators, compute m, r=1 ----------------
__global__ __launch_bounds__(1024) void k_init(const int* __restrict__ idx,
                                               float* __restrict__ colsum,
                                               float* __restrict__ rv,
                                               float* __restrict__ scal) {
    __shared__ int red[1024];
    const int tid = threadIdx.x;
    int cnt = 0;
    for (int q = tid; q < NB; q += 1024) {
        colsum[q] = 0.f;
        rv[q] = 1.f;
        cnt += (idx[q] == 1) ? 1 : 0;
    }
    red[tid] = cnt; __syncthreads();
    for (int s = 512; s > 0; s >>= 1) {
        if (tid < s) red[tid] += red[tid + s];
        __syncthreads();
    }
    if (tid == 0) {
        const int c1 = red[0];
        scal[0] = (float)c1 + 0.1f * (float)(NB - c1);   // m
        scal[1] = 0.f;                                   // asl accumulator
        scal[2] = 0.f;                                   // multiclass accumulator
    }
}

// ---------------- f32 -> bf16 convert (vectorized) ----------------
__global__ __launch_bounds__(256) void k_cvt(const float4* __restrict__ src,
                                             unsigned short* __restrict__ dst, int n4) {
    const int i = blockIdx.x * 256 + threadIdx.x;
    if (i >= n4) return;
    const float4 v = src[i];
    union { unsigned short h[4]; uint2 u; } p;
    p.h[0] = f2bf(v.x); p.h[1] = f2bf(v.y); p.h[2] = f2bf(v.z); p.h[3] = f2bf(v.w);
    ((uint2*)dst)[i] = p.u;
}

// ---------------- GEMM: sim = (F @ T^T) * (1/0.07), bf16 MFMA ----------------
// 128x128 tile, BK=64, 4 waves (2x2), 16x16x32 MFMA, XOR-swizzled LDS,
// global_load_lds width 16 with pre-swizzled global source.
// fused=1: write masked coco/cifar directly (no sim buffer, no mask pass).
__global__ __launch_bounds__(256) void k_gemm(const unsigned short* __restrict__ Fb,
                                              const unsigned short* __restrict__ Tb,
                                              const int* __restrict__ idx,
                                              float* __restrict__ sim,
                                              float* __restrict__ coco,
                                              float* __restrict__ cifar,
                                              int fused) {
    __shared__ unsigned short lA[128 * 64];   // 16 KB, [row][k] bf16, swizzled
    __shared__ unsigned short lB[128 * 64];   // 16 KB
    const int tid  = threadIdx.x;
    const int lane = tid & 63;
    const int wid  = tid >> 6;                // 0..3
    const int wm = wid >> 1, wn = wid & 1;    // 2x2 wave grid, 64x64 each
    const int brow = blockIdx.y * 128;
    const int bcol = blockIdx.x * 128;

    f32x4 acc[4][4] = {};

    for (int kt = 0; kt < ND / 64; ++kt) {
        if (kt) __syncthreads();
#pragma unroll
        for (int c = 0; c < 4; ++c) {
            const int ch  = c * 4 + wid;
            const int o   = ch * 1024 + lane * 16;   // linear LDS byte
            const int row = o >> 7;                  // 128 B per row
            const int kbu = (o & 127) ^ ((row & 7) << 4); // inverse-swizzled source
            const unsigned short* gA = Fb + ((size_t)(brow + row) << 9) + (kt << 5)*2 + (kbu >> 1);
            __builtin_amdgcn_global_load_lds(
                (const __attribute__((address_space(1))) unsigned int*)gA,
                (__attribute__((address_space(3))) unsigned int*)((char*)lA + ch * 1024),
                16, 0, 0);
            const unsigned short* gB = Tb + ((size_t)(bcol + row) << 9) + (kt << 5)*2 + (kbu >> 1);
            __builtin_amdgcn_global_load_lds(
                (const __attribute__((address_space(1))) unsigned int*)gB,
                (__attribute__((address_space(3))) unsigned int*)((char*)lB + ch * 1024),
                16, 0, 0);
        }
        __syncthreads();
#pragma unroll
        for (int ks = 0; ks < 2; ++ks) {
            u32x4 af[4], bfr[4];
#pragma unroll
            for (int mi = 0; mi < 4; ++mi) {
                const int row  = wm * 64 + mi * 16 + (lane & 15);
                const int kb   = ks * 64 + ((lane >> 4) << 4);
                const int addr = row * 128 + (kb ^ ((row & 7) << 4));
                af[mi] = *(const u32x4*)((const char*)lA + addr);
            }
#pragma unroll
            for (int ni = 0; ni < 4; ++ni) {
                const int row  = wn * 64 + ni * 16 + (lane & 15);
                const int kb   = ks * 64 + ((lane >> 4) << 4);
                const int addr = row * 128 + (kb ^ ((row & 7) << 4));
                bfr[ni] = *(const u32x4*)((const char*)lB + addr);
            }
#pragma unroll
            for (int mi = 0; mi < 4; ++mi)
#pragma unroll
                for (int ni = 0; ni < 4; ++ni)
                    asm("v_mfma_f32_16x16x32_bf16 %0, %1, %2, %0"
                        : "+v"(acc[mi][ni]) : "v"(af[mi]), "v"(bfr[ni]));
        }
    }
    asm volatile("s_nop 7\n\ts_nop 7\n\ts_nop 7" ::);   // MFMA->VALU hazard fence
    if (fused) {
#pragma unroll
        for (int mi = 0; mi < 4; ++mi) {
            const int rb = brow + wm * 64 + mi * 16 + ((lane >> 4) << 2);
            int fl[4];
#pragma unroll
            for (int rr = 0; rr < 4; ++rr) fl[rr] = (idx[rb + rr] == 1);
#pragma unroll
            for (int ni = 0; ni < 4; ++ni) {
                const int col = bcol + wn * 64 + ni * 16 + (lane & 15);
#pragma unroll
                for (int rr = 0; rr < 4; ++rr) {
                    const float s = acc[mi][ni][rr] * INV_TEMP;
                    const size_t o = (size_t)(rb + rr) * NC + col;
                    coco[o]  = fl[rr] ? 0.0f : s;
                    cifar[o] = fl[rr] ? s : 0.0f;
                }
            }
        }
    } else {
#pragma unroll
        for (int mi = 0; mi < 4; ++mi) {
            const int rb = brow + wm * 64 + mi * 16 + ((lane >> 4) << 2);
#pragma unroll
            for (int ni = 0; ni < 4; ++ni) {
                const int col = bcol + wn * 64 + ni * 16 + (lane & 15);
#pragma unroll
                for (int rr = 0; rr < 4; ++rr)
                    sim[(size_t)(rb + rr) * NC + col] = acc[mi][ni][rr] * INV_TEMP;
            }
        }
    }
}

// ---------------- per-row stats + ASL loss (one block per row) ----------------
// Fast ASL: sigmoid from shared exp, pow via exp2/log2 builtins.
// Optionally writes Ebf[i][c] = bf16(exp(sim)) for reuse by colsum/rowfinal.
__global__ __launch_bounds__(256) void k_stats(const float* __restrict__ pc,
                                               const float* __restrict__ pf,
                                               const int* __restrict__ idx,
                                               const float* __restrict__ tgt,
                                               unsigned short* __restrict__ Ebf,
                                               float* __restrict__ rowsum0,
                                               float* __restrict__ simdiag,
                                               float* __restrict__ Arow,
                                               float* __restrict__ Tsumv,
                                               float* __restrict__ rowmx,
                                               float* __restrict__ rowmn,
                                               float* __restrict__ scal) {
    const int i = blockIdx.x, tid = threadIdx.x;
    const float* srow = ((idx[i] == 1) ? pf : pc) + (size_t)i * NC;
    const float* trow = tgt + (size_t)i * NC;
    unsigned short* erow = Ebf ? (Ebf + (size_t)i * NC) : nullptr;
    float rs = 0.f, a = 0.f, ts = 0.f, ls = 0.f;
    float mx = -3.4e38f, mn = 3.4e38f;
    for (int c = tid * 4; c < NC; c += 1024) {
        const float s0 = srow[c], s1 = srow[c+1], s2 = srow[c+2], s3 = srow[c+3];
        const float4 t4 = *(const float4*)(trow + c);
        const float t0 = t4.x, t1 = t4.y, t2 = t4.z, t3 = t4.w;
        if ((unsigned)(i - c) < 4u)
            simdiag[i] = (i == c) ? s0 : ((i == c+1) ? s1 : ((i == c+2) ? s2 : s3));
        float e0, e1, e2, e3;
#define ASL(sv, tv, ev) { \
        ev = __expf(sv); \
        rs += ev; a += (tv) * ev; ts += (tv); \
        mx = fmaxf(mx, (sv)); mn = fminf(mn, (sv)); \
        const float inv = __builtin_amdgcn_rcpf(1.0f + ev); \
        const float xsp = ev * inv; \
        const float xsn = fminf(1.05f - xsp, 1.0f); \
        const float lp  = __logf(xsp); \
        const float ln  = __logf(xsn); \
        const float pt  = xsn + (tv) * (xsp - xsn); \
        const float g   = 4.0f - 3.0f * (tv); \
        const float pw  = __builtin_amdgcn_exp2f(g * __builtin_amdgcn_logf(1.0f - pt)); \
        ls += (ln + (tv) * (lp - ln)) * pw; }
        ASL(s0, t0, e0) ASL(s1, t1, e1) ASL(s2, t2, e2) ASL(s3, t3, e3)
#undef ASL
        if (erow) {
            uint2 w;
            w.x = (unsigned)f2bf(e0) | ((unsigned)f2bf(e1) << 16);
            w.y = (unsigned)f2bf(e2) | ((unsigned)f2bf(e3) << 16);
            *(uint2*)(erow + c) = w;
        }
    }
#pragma unroll
    for (int off = 1; off < 64; off <<= 1) {
        rs += __shfl_xor(rs, off);
        a  += __shfl_xor(a , off);
        ts += __shfl_xor(ts, off);
        ls += __shfl_xor(ls, off);
        mx = fmaxf(mx, __shfl_xor(mx, off));
        mn = fminf(mn, __shfl_xor(mn, off));
    }
    __shared__ float red[4][6];
    if ((tid & 63) == 0) {
        const int w = tid >> 6;
        red[w][0] = rs; red[w][1] = a; red[w][2] = ts;
        red[w][3] = ls; red[w][4] = mx; red[w][5] = mn;
    }
    __syncthreads();
    if (tid == 0) {
        rowsum0[i] = red[0][0] + red[1][0] + red[2][0] + red[3][0];
        Arow[i]    = red[0][1] + red[1][1] + red[2][1] + red[3][1];
        Tsumv[i]   = red[0][2] + red[1][2] + red[2][2] + red[3][2];
        atomicAdd(&scal[1], red[0][3] + red[1][3] + red[2][3] + red[3][3]);
        rowmx[i] = fmaxf(fmaxf(red[0][4], red[1][4]), fmaxf(red[2][4], red[3][4]));
        rowmn[i] = fminf(fminf(red[0][5], red[1][5]), fminf(red[2][5], red[3][5]));
    }
}

// ---------------- colsum from cached bf16 E:  colsum[j] = sum_i E[i][j]*r[i] ----------------
// 16 rows per block (gridy = 256) -> 1024 blocks = 16 waves/CU for latency hiding.
__global__ __launch_bounds__(256) void k_colsum_e(const unsigned short* __restrict__ Ebf,
                                                  const float* __restrict__ rv,
                                                  float* __restrict__ colsum) {
    const int j  = (blockIdx.x * 256 + threadIdx.x) * 4;   // gridx = NB/1024 = 4
    const int i0 = blockIdx.y * 16;                        // gridy = 256
    float a0 = 0.f, a1 = 0.f, a2 = 0.f, a3 = 0.f;
    for (int i = i0; i < i0 + 16; ++i) {
        const uint2 u = *(const uint2*)(Ebf + (size_t)i * NC + j);
        const float r = rv[i];
        a0 += bflo(u.x) * r;
        a1 += bfhi(u.x) * r;
        a2 += bflo(u.y) * r;
        a3 += bfhi(u.y) * r;
    }
    atomicAdd(&colsum[j    ], a0);
    atomicAdd(&colsum[j + 1], a1);
    atomicAdd(&colsum[j + 2], a2);
    atomicAdd(&colsum[j + 3], a3);
}

// ---------------- fallback colsum (no E buffer) ----------------
__global__ __launch_bounds__(256) void k_colsum(const float* __restrict__ pc,
                                                const float* __restrict__ pf,
                                                const int* __restrict__ idx,
                                                const float* __restrict__ rv,
                                                float* __restrict__ colsum) {
    const int j  = (blockIdx.x * 256 + threadIdx.x) * 4;   // gridx = NB/1024 = 4
    const int i0 = blockIdx.y * 32;                        // gridy = 128
    float a0 = 0.f, a1 = 0.f, a2 = 0.f, a3 = 0.f;
    for (int i = i0; i < i0 + 32; ++i) {
        const float* row = ((idx[i] == 1) ? pf : pc) + (size_t)i * NC;
        const float r = rv[i];
        a0 += __expf(row[j    ]) * r;
        a1 += __expf(row[j + 1]) * r;
        a2 += __expf(row[j + 2]) * r;
        a3 += __expf(row[j + 3]) * r;
    }
    atomicAdd(&colsum[j    ], a0);
    atomicAdd(&colsum[j + 1], a1);
    atomicAdd(&colsum[j + 2], a2);
    atomicAdd(&colsum[j + 3], a3);
}

// ---------------- per-iteration scalar update of r ----------------
__global__ __launch_bounds__(1024) void k_update(const float* __restrict__ simdiag,
                                                 float* __restrict__ colsum,
                                                 const float* __restrict__ rowsum0,
                                                 float* __restrict__ rv,
                                                 const float* __restrict__ scal) {
    __shared__ float red[1024];
    const int tid = threadIdx.x;
    float part = 0.f;
    float rl[4];
#pragma unroll
    for (int q = 0; q < 4; ++q) {
        const int i = tid + q * 1024;
        const float d  = fminf(simdiag[i] / colsum[i], 1.0f);
        const float rn = rv[i] * d;
        rl[q] = rn;
        part += rn * rowsum0[i];
        colsum[i] = 0.f;                    // reset for next iteration
    }
    red[tid] = part; __syncthreads();
    for (int s = 512; s > 0; s >>= 1) {
        if (tid < s) red[tid] += red[tid + s];
        __syncthreads();
    }
    const float sc = scal[0] / red[0];      // m / P.sum()
#pragma unroll
    for (int q = 0; q < 4; ++q) rv[tid + q * 1024] = rl[q] * sc;
}

// ---------------- logsumexp(P row) + multiclass accumulation, from bf16 E ----------------
__global__ __launch_bounds__(256) void k_rowfinal_e(const unsigned short* __restrict__ Ebf,
                                                    const float* __restrict__ rv,
                                                    const float* __restrict__ Arow,
                                                    const float* __restrict__ Tsumv,
                                                    const float* __restrict__ rowmx,
                                                    const float* __restrict__ rowmn,
                                                    float* __restrict__ scal) {
    const int i = blockIdx.x, tid = threadIdx.x;
    const float ri = rv[i];
    const unsigned short* erow = Ebf + (size_t)i * NC;
    // max of P row: ri>=0 -> ri*exp(rowmax); ri<0 -> ri*exp(rowmin).
    // (bf16 E can exceed exp(rowmax) by ~0.4%; logsumexp stays valid for any finite M)
    const float M = ri * __expf((ri >= 0.f) ? rowmx[i] : rowmn[i]);
    float se = 0.f;
    for (int c = tid * 8; c < NC; c += 2048) {
        const uint4 u = *(const uint4*)(erow + c);
        se += __expf(ri * bflo(u.x) - M);
        se += __expf(ri * bfhi(u.x) - M);
        se += __expf(ri * bflo(u.y) - M);
        se += __expf(ri * bfhi(u.y) - M);
        se += __expf(ri * bflo(u.z) - M);
        se += __expf(ri * bfhi(u.z) - M);
        se += __expf(ri * bflo(u.w) - M);
        se += __expf(ri * bfhi(u.w) - M);
    }
#pragma unroll
    for (int off = 1; off < 64; off <<= 1) se += __shfl_xor(se, off);
    __shared__ float red[4];
    if ((tid & 63) == 0) red[tid >> 6] = se;
    __syncthreads();
    if (tid == 0) {
        const float L = M + __logf(red[0] + red[1] + red[2] + red[3]);
        atomicAdd(&scal[2], Tsumv[i] * L - ri * Arow[i]);
    }
}

// ---------------- fallback rowfinal (no E buffer) ----------------
__global__ __launch_bounds__(256) void k_rowfinal(const float* __restrict__ pc,
                                                  const float* __restrict__ pf,
                                                  const int* __restrict__ idx,
                                                  const float* __restrict__ rv,
                                                  const float* __restrict__ Arow,
                                                  const float* __restrict__ Tsumv,
                                                  const float* __restrict__ rowmx,
                                                  const float* __restrict__ rowmn,
                                                  float* __restrict__ scal) {
    const int i = blockIdx.x, tid = threadIdx.x;
    const float ri = rv[i];
    const float* srow = ((idx[i] == 1) ? pf : pc) + (size_t)i * NC;
    const float M = ri * __expf((ri >= 0.f) ? rowmx[i] : rowmn[i]);
    float se = 0.f;
    for (int c = tid * 4; c < NC; c += 1024) {
        se += __expf(ri * __expf(srow[c    ]) - M);
        se += __expf(ri * __expf(srow[c + 1]) - M);
        se += __expf(ri * __expf(srow[c + 2]) - M);
        se += __expf(ri * __expf(srow[c + 3]) - M);
    }
#pragma unroll
    for (int off = 1; off < 64; off <<= 1) se += __shfl_xor(se, off);
    __shared__ float red[4];
    if ((tid & 63) == 0) red[tid >> 6] = se;
    __syncthreads();
    if (tid == 0) {
        const float L = M + __logf(red[0] + red[1] + red[2] + red[3]);
        atomicAdd(&scal[2], Tsumv[i] * L - ri * Arow[i]);
    }
}

// ---------------- final scalars ----------------
__global__ void k_scalars(const float* __restrict__ scal, float* __restrict__ out) {
    if (threadIdx.x == 0) {
        const float mc = scal[2] / (float)NB;
        const float ml = -scal[1];
        out[0] = mc + ml;
        out[1] = mc;
        out[2] = ml;
    }
}

// ---------------- masked sim outputs (fallback path; sim aliases cifar) ----------------
__global__ __launch_bounds__(256) void k_mask(const float* sim, const int* idx,
                                              float* coco, float* cifar) {
    const int i = blockIdx.y;
    const int c = blockIdx.x * 256 + threadIdx.x;
    const size_t o = (size_t)i * NC + c;
    const float s = sim[o];                 // read before any aliased write
    const bool isCifar = (idx[i] == 1);
    coco[o]  = isCifar ? 0.0f : s;
    cifar[o] = isCifar ? s : 0.0f;
}

extern "C" void kernel_launch(void* const* d_in, const int* in_sizes, int n_in,
                              void* d_out, int out_size, void* d_ws, size_t ws_size,
                              hipStream_t stream) {
    const float* F   = (const float*)d_in[0];   // [4096,512]
    const float* T   = (const float*)d_in[1];   // [8192,512]
    const float* tgt = (const float*)d_in[2];   // [4096,8192]
    const int*   idx = (const int*)d_in[3];     // [4096]

    float* out   = (float*)d_out;
    float* coco  = out + 3;
    float* cifar = coco + (size_t)NB * NC;

    const size_t FbBytes    = (size_t)NB * ND * 2;      // 4 MB
    const size_t TbBytes    = (size_t)NC * ND * 2;      // 8 MB
    const size_t EBytes     = (size_t)NB * NC * 2;      // 67 MB
    const size_t smallBytes = 10 * (size_t)NB * 4 + 1024;

    const bool fused = (d_ws != nullptr) &&
                       (ws_size >= FbBytes + TbBytes + smallBytes + 512);
    const bool hasE  = (d_ws != nullptr) &&
                       (ws_size >= FbBytes + TbBytes + EBytes + smallBytes + 512);
    unsigned short *Fb, *Tb, *Ebf = nullptr;
    float *sm, *sim;
    if (fused) {
        Fb  = (unsigned short*)d_ws;
        Tb  = (unsigned short*)((char*)d_ws + FbBytes);
        char* p = (char*)d_ws + FbBytes + TbBytes;
        if (hasE) { Ebf = (unsigned short*)p; p += EBytes; }
        sm  = (float*)p;
        sim = nullptr;
    } else {
        // sim lives in the cifar output slot; bf16 copies + small vectors in the
        // coco slot head (dead until k_mask, which runs last).
        sim = cifar;
        char* base = (char*)(((uintptr_t)(void*)coco + 255) & ~(uintptr_t)255);
        Fb  = (unsigned short*)base;
        Tb  = (unsigned short*)(base + FbBytes);
        sm  = (float*)(base + FbBytes + TbBytes);
    }
    float* colsum  = sm;
    float* rv      = sm + NB;
    float* rowsum0 = sm + 2 * NB;
    float* simdiag = sm + 3 * NB;
    float* Arow    = sm + 4 * NB;
    float* Tsumv   = sm + 5 * NB;
    float* rowmx   = sm + 6 * NB;
    float* rowmn   = sm + 7 * NB;
    float* scal    = sm + 8 * NB;

    const float* pc = fused ? coco  : sim;
    const float* pf = fused ? cifar : sim;

    k_init<<<1, 1024, 0, stream>>>(idx, colsum, rv, scal);
    k_cvt<<<(NB * ND / 4) / 256, 256, 0, stream>>>((const float4*)F, Fb, NB * ND / 4);
    k_cvt<<<(NC * ND / 4) / 256, 256, 0, stream>>>((const float4*)T, Tb, NC * ND / 4);
    k_gemm<<<dim3(NC / 128, NB / 128), 256, 0, stream>>>(Fb, Tb, idx, sim, coco, cifar,
                                                         fused ? 1 : 0);
    k_stats<<<NB, 256, 0, stream>>>(pc, pf, idx, tgt, Ebf, rowsum0, simdiag, Arow, Tsumv,
                                    rowmx, rowmn, scal);
    for (int it = 0; it < 5; ++it) {
        if (hasE)
            k_colsum_e<<<dim3(NB / 1024, 256), 256, 0, stream>>>(Ebf, rv, colsum);
        else
            k_colsum<<<dim3(NB / 1024, 128), 256, 0, stream>>>(pc, pf, idx, rv, colsum);
        k_update<<<1, 1024, 0, stream>>>(simdiag, colsum, rowsum0, rv, scal);
    }
    if (hasE)
        k_rowfinal_e<<<NB, 256, 0, stream>>>(Ebf, rv, Arow, Tsumv, rowmx, rowmn, scal);
    else
        k_rowfinal<<<NB, 256, 0, stream>>>(pc, pf, idx, rv, Arow, Tsumv, rowmx, rowmn, scal);
    k_scalars<<<1, 64, 0, stream>>>(scal, out);
    if (!fused) k_mask<<<dim3(NC / 256, NB), 256, 0, stream>>>(sim, idx, coco, cifar);
}